// Round 14
// baseline (137.698 us; speedup 1.0000x reference)
//
#include <hip/hip_runtime.h>
#include <hip/hip_bf16.h>

#define NN 10000
#define EE 320000
#define ET (EE + NN)   // edges + self loops
#define FIN 256
#define CAP 128        // padded-CSR row capacity; P(deg>96) ~ e^-41, CAP=128 safe
#define GEMM1_BLOCKS ((NN + 63) / 64)          // 157
#define SCAT_BLOCKS ((ET + 255) / 256)         // 1290

// bf16 <-> f32 helpers (bf16->f32 exact; f32->bf16 round-to-nearest-even)
__device__ __forceinline__ float bf2f(unsigned short u) {
    return __uint_as_float(((unsigned)u) << 16);
}
__device__ __forceinline__ unsigned short f2bf(float f) {
    unsigned u = __float_as_uint(f);
    u += 0x7FFFu + ((u >> 16) & 1u);
    return (unsigned short)(u >> 16);
}
// unpack 8 bf16 (uint4) -> 8 floats
__device__ __forceinline__ void bf8_unpack(uint4 q, float* f) {
    f[0] = __uint_as_float((q.x & 0xFFFFu) << 16);
    f[1] = __uint_as_float(q.x & 0xFFFF0000u);
    f[2] = __uint_as_float((q.y & 0xFFFFu) << 16);
    f[3] = __uint_as_float(q.y & 0xFFFF0000u);
    f[4] = __uint_as_float((q.z & 0xFFFFu) << 16);
    f[5] = __uint_as_float(q.z & 0xFFFF0000u);
    f[6] = __uint_as_float((q.w & 0xFFFFu) << 16);
    f[7] = __uint_as_float(q.w & 0xFFFF0000u);
}

// ---------------- fused: layer-1 GEMM (+att scores), padded-CSR scatter, watt ----------------

__global__ __launch_bounds__(256) void k_gemm1_scatter(
        const float* __restrict__ x, const float* __restrict__ W1,
        const float* __restrict__ as1, const float* __restrict__ ad1,
        const int* __restrict__ ei, int* __restrict__ cnt, int* __restrict__ csr,
        const float* __restrict__ W2, const float* __restrict__ as2,
        const float* __restrict__ ad2, float* __restrict__ wsrc, float* __restrict__ wdst,
        unsigned short* __restrict__ xl1, float* __restrict__ a_src1,
        float* __restrict__ a_dst1) {
    int tid = threadIdx.x;
    if (blockIdx.x >= GEMM1_BLOCKS + SCAT_BLOCKS) {
        // watt block
        if (tid < 128) {
            int k = tid & 63;
            const float* av = (tid < 64) ? as2 : ad2;
            float acc = 0.f;
#pragma unroll
            for (int c4 = 0; c4 < 64; c4++) {
                float4 w = *(const float4*)&W2[k * 256 + c4 * 4];
                float4 a = *(const float4*)&av[c4 * 4];
                acc += w.x * a.x + w.y * a.y + w.z * a.z + w.w * a.w;
            }
            if (tid < 64) wsrc[k] = acc; else wdst[k] = acc;
        }
        return;
    }
    if (blockIdx.x >= GEMM1_BLOCKS) {
        int e = (blockIdx.x - GEMM1_BLOCKS) * 256 + tid;
        if (e < ET) {
            int s, d;
            if (e < EE) { s = ei[e]; d = ei[EE + e]; }
            else        { s = e - EE; d = s; }
            int slot = atomicAdd(&cnt[d], 1);
            csr[d * CAP + slot] = s;
        }
        return;
    }
    __shared__ float xst[32][68];   // [k][row], padded
    __shared__ float ws[32][64];    // [k][col]
    int nb = blockIdx.x * 64;
    int r0 = (tid >> 4) * 4;
    int c0 = (tid & 15) * 4;

    float4 acc[4];
#pragma unroll
    for (int i = 0; i < 4; i++) acc[i] = make_float4(0.f, 0.f, 0.f, 0.f);

    int srow = tid >> 3;
    int skf  = (tid & 7) * 4;

    for (int kt = 0; kt < 8; kt++) {
#pragma unroll
        for (int h = 0; h < 2; h++) {
            int row = srow + h * 32;
            int rg = nb + row; if (rg > NN - 1) rg = NN - 1;
            float4 xv = *(const float4*)&x[rg * FIN + kt * 32 + skf];
            xst[skf + 0][row] = xv.x;
            xst[skf + 1][row] = xv.y;
            xst[skf + 2][row] = xv.z;
            xst[skf + 3][row] = xv.w;
        }
        int wk = tid >> 4;
#pragma unroll
        for (int h = 0; h < 2; h++) {
            int k = wk + h * 16;
            *(float4*)&ws[k][c0] = *(const float4*)&W1[(kt * 32 + k) * 64 + c0];
        }
        __syncthreads();
#pragma unroll
        for (int k = 0; k < 32; k++) {
            float4 a = *(const float4*)&xst[k][r0];
            float4 b = *(const float4*)&ws[k][c0];
            acc[0].x += a.x * b.x; acc[0].y += a.x * b.y; acc[0].z += a.x * b.z; acc[0].w += a.x * b.w;
            acc[1].x += a.y * b.x; acc[1].y += a.y * b.y; acc[1].z += a.y * b.z; acc[1].w += a.y * b.w;
            acc[2].x += a.z * b.x; acc[2].y += a.z * b.y; acc[2].z += a.z * b.z; acc[2].w += a.z * b.w;
            acc[3].x += a.w * b.x; acc[3].y += a.w * b.y; acc[3].z += a.w * b.z; acc[3].w += a.w * b.w;
        }
        __syncthreads();
    }

    float4 asv = *(const float4*)&as1[c0];
    float4 adv = *(const float4*)&ad1[c0];
#pragma unroll
    for (int i = 0; i < 4; i++) {
        int n = nb + r0 + i;
        bool ok = (n < NN);
        if (ok) {
            ushort4 q;
            q.x = f2bf(acc[i].x); q.y = f2bf(acc[i].y);
            q.z = f2bf(acc[i].z); q.w = f2bf(acc[i].w);
            *(ushort4*)&xl1[n * 64 + c0] = q;       // bf16 row, 8B store
        }
        float ps = acc[i].x * asv.x + acc[i].y * asv.y + acc[i].z * asv.z + acc[i].w * asv.w;
        float pd = acc[i].x * adv.x + acc[i].y * adv.y + acc[i].z * adv.z + acc[i].w * adv.w;
        ps += __shfl_xor(ps, 1);
        pd += __shfl_xor(pd, 1);
        if (ok && (tid & 1) == 0) {
            a_src1[n * 8 + (c0 >> 3)] = ps;
            a_dst1[n * 8 + (c0 >> 3)] = pd;
        }
    }
}

// ---------------- GAT layer 1: 4 dsts/block, 8-lane subgroups x 4-deep (32 edges/iter) -------

__global__ __launch_bounds__(256) void k_gat1(
        const int* __restrict__ cnt, const int* __restrict__ csr,
        const unsigned short* __restrict__ xl1, const float* __restrict__ a_src1,
        const float* __restrict__ a_dst1, const float* __restrict__ b1,
        const float* __restrict__ wsrc, const float* __restrict__ wdst,
        unsigned short* __restrict__ hout, float* __restrict__ a_src2,
        float* __restrict__ a_dst2) {
    int d = blockIdx.x * 4 + (threadIdx.x >> 6);
    int l = threadIdx.x & 63;
    int eg = l >> 3;            // 8 edge-subgroups
    int hd = l & 7;             // lane's head == its channel-octet
    int c0 = hd * 8;            // 8 channels per lane
    float adst = a_dst1[d * 8 + hd];
    const int* row = csr + d * CAP;
    int re = cnt[d];
    float den = 0.f;
    float acc[8];
#pragma unroll
    for (int j = 0; j < 8; j++) acc[j] = 0.f;
    for (int i = eg; i < re; i += 32) {        // 4 predicated edges per subgroup-iter
        int j1 = i + 8, j2 = i + 16, j3 = i + 24;
        bool v1 = j1 < re, v2 = j2 < re, v3 = j3 < re;
        int s0 = row[i];
        int s1 = row[v1 ? j1 : i];
        int s2 = row[v2 ? j2 : i];
        int s3 = row[v3 ? j3 : i];
        float a0 = a_src1[s0 * 8 + hd];
        float a1 = a_src1[s1 * 8 + hd];
        float a2 = a_src1[s2 * 8 + hd];
        float a3 = a_src1[s3 * 8 + hd];
        uint4 q0 = *(const uint4*)&xl1[s0 * 64 + c0];
        uint4 q1 = *(const uint4*)&xl1[s1 * 64 + c0];
        uint4 q2 = *(const uint4*)&xl1[s2 * 64 + c0];
        uint4 q3 = *(const uint4*)&xl1[s3 * 64 + c0];
        float e0 = a0 + adst; e0 = (e0 > 0.f) ? e0 : 0.2f * e0;
        float e1 = a1 + adst; e1 = (e1 > 0.f) ? e1 : 0.2f * e1;
        float e2 = a2 + adst; e2 = (e2 > 0.f) ? e2 : 0.2f * e2;
        float e3 = a3 + adst; e3 = (e3 > 0.f) ? e3 : 0.2f * e3;
        float w0 = __expf(e0);
        float w1 = v1 ? __expf(e1) : 0.f;
        float w2 = v2 ? __expf(e2) : 0.f;
        float w3 = v3 ? __expf(e3) : 0.f;
        den += (w0 + w1) + (w2 + w3);
        float f0[8], f1[8], f2[8], f3[8];
        bf8_unpack(q0, f0); bf8_unpack(q1, f1); bf8_unpack(q2, f2); bf8_unpack(q3, f3);
#pragma unroll
        for (int j = 0; j < 8; j++)
            acc[j] += (w0 * f0[j] + w1 * f1[j]) + (w2 * f2[j] + w3 * f3[j]);
    }
    // reduce over the 8 edge-subgroups
    den += __shfl_xor(den, 8); den += __shfl_xor(den, 16); den += __shfl_xor(den, 32);
#pragma unroll
    for (int j = 0; j < 8; j++) {
        acc[j] += __shfl_xor(acc[j], 8);
        acc[j] += __shfl_xor(acc[j], 16);
        acc[j] += __shfl_xor(acc[j], 32);
    }
    float inv = 1.f / den;
    float o[8];
#pragma unroll
    for (int j = 0; j < 8; j++) {
        float v = acc[j] * inv + b1[c0 + j];
        o[j] = (v > 0.f) ? v : (__expf(v) - 1.f);
    }
    if (eg == 0) {
        uint4 q;
        q.x = (unsigned)f2bf(o[0]) | ((unsigned)f2bf(o[1]) << 16);
        q.y = (unsigned)f2bf(o[2]) | ((unsigned)f2bf(o[3]) << 16);
        q.z = (unsigned)f2bf(o[4]) | ((unsigned)f2bf(o[5]) << 16);
        q.w = (unsigned)f2bf(o[6]) | ((unsigned)f2bf(o[7]) << 16);
        *(uint4*)&hout[d * 64 + c0] = q;            // bf16 row, 16B store
    }
    // fused layer-2 scores: a2[d] = h[d] . (W2@att2)
    float ps = 0.f, pd = 0.f;
#pragma unroll
    for (int j = 0; j < 8; j++) {
        ps += o[j] * wsrc[c0 + j];
        pd += o[j] * wdst[c0 + j];
    }
    ps += __shfl_xor(ps, 1); ps += __shfl_xor(ps, 2); ps += __shfl_xor(ps, 4);
    pd += __shfl_xor(pd, 1); pd += __shfl_xor(pd, 2); pd += __shfl_xor(pd, 4);
    if (l == 0) { a_src2[d] = ps; a_dst2[d] = pd; }
}

// ---------------- GAT layer 2 + output GEMM fused (8-lane subgroups x 4-deep) ----------------

__global__ __launch_bounds__(256) void k_gat2_out(
        const int* __restrict__ cnt, const int* __restrict__ csr,
        const unsigned short* __restrict__ hbuf, const float* __restrict__ a_src2,
        const float* __restrict__ a_dst2, const float* __restrict__ W2,
        const float* __restrict__ b2, float* __restrict__ out) {
    __shared__ float sagg[4][64];
    int wid = threadIdx.x >> 6;
    int d = blockIdx.x * 4 + wid;
    int l = threadIdx.x & 63;
    int eg = l >> 3;
    int c0 = (l & 7) * 8;
    float adst = a_dst2[d];
    const int* row = csr + d * CAP;
    int re = cnt[d];
    float den = 0.f;
    float acc[8];
#pragma unroll
    for (int j = 0; j < 8; j++) acc[j] = 0.f;
    for (int i = eg; i < re; i += 32) {        // 4 predicated edges per subgroup-iter
        int j1 = i + 8, j2 = i + 16, j3 = i + 24;
        bool v1 = j1 < re, v2 = j2 < re, v3 = j3 < re;
        int s0 = row[i];
        int s1 = row[v1 ? j1 : i];
        int s2 = row[v2 ? j2 : i];
        int s3 = row[v3 ? j3 : i];
        float a0 = a_src2[s0];
        float a1 = a_src2[s1];
        float a2 = a_src2[s2];
        float a3 = a_src2[s3];
        uint4 q0 = *(const uint4*)&hbuf[s0 * 64 + c0];
        uint4 q1 = *(const uint4*)&hbuf[s1 * 64 + c0];
        uint4 q2 = *(const uint4*)&hbuf[s2 * 64 + c0];
        uint4 q3 = *(const uint4*)&hbuf[s3 * 64 + c0];
        float e0 = a0 + adst; e0 = (e0 > 0.f) ? e0 : 0.2f * e0;
        float e1 = a1 + adst; e1 = (e1 > 0.f) ? e1 : 0.2f * e1;
        float e2 = a2 + adst; e2 = (e2 > 0.f) ? e2 : 0.2f * e2;
        float e3 = a3 + adst; e3 = (e3 > 0.f) ? e3 : 0.2f * e3;
        float w0 = __expf(e0);
        float w1 = v1 ? __expf(e1) : 0.f;
        float w2 = v2 ? __expf(e2) : 0.f;
        float w3 = v3 ? __expf(e3) : 0.f;
        den += (w0 + w1) + (w2 + w3);
        float f0[8], f1[8], f2[8], f3[8];
        bf8_unpack(q0, f0); bf8_unpack(q1, f1); bf8_unpack(q2, f2); bf8_unpack(q3, f3);
#pragma unroll
        for (int j = 0; j < 8; j++)
            acc[j] += (w0 * f0[j] + w1 * f1[j]) + (w2 * f2[j] + w3 * f3[j]);
    }
    den += __shfl_xor(den, 8); den += __shfl_xor(den, 16); den += __shfl_xor(den, 32);
#pragma unroll
    for (int j = 0; j < 8; j++) {
        acc[j] += __shfl_xor(acc[j], 8);
        acc[j] += __shfl_xor(acc[j], 16);
        acc[j] += __shfl_xor(acc[j], 32);
    }
    if (eg == 0) {
        float inv = 1.f / den;
        *(float4*)&sagg[wid][c0] =
            make_float4(acc[0] * inv, acc[1] * inv, acc[2] * inv, acc[3] * inv);
        *(float4*)&sagg[wid][c0 + 4] =
            make_float4(acc[4] * inv, acc[5] * inv, acc[6] * inv, acc[7] * inv);
    }
    __syncthreads();
    // matvec: thread c computes column c for all 4 dsts of this block
    int c = threadIdx.x;
    float o0 = 0.f, o1 = 0.f, o2 = 0.f, o3 = 0.f;
#pragma unroll 8
    for (int k = 0; k < 64; k++) {
        float w = W2[k * 256 + c];          // coalesced, L2-hit
        o0 += sagg[0][k] * w;               // LDS broadcasts
        o1 += sagg[1][k] * w;
        o2 += sagg[2][k] * w;
        o3 += sagg[3][k] * w;
    }
    float bc = b2[c];
    int nb = blockIdx.x * 4;
    out[(nb + 0) * 256 + c] = o0 + bc;
    out[(nb + 1) * 256 + c] = o1 + bc;
    out[(nb + 2) * 256 + c] = o2 + bc;
    out[(nb + 3) * 256 + c] = o3 + bc;
}

// ---------------- launch ----------------

extern "C" void kernel_launch(void* const* d_in, const int* in_sizes, int n_in,
                              void* d_out, int out_size, void* d_ws, size_t ws_size,
                              hipStream_t stream) {
    const float* x   = (const float*)d_in[0];
    const int*   ei  = (const int*)d_in[1];
    const float* W1  = (const float*)d_in[2];
    const float* as1 = (const float*)d_in[3];
    const float* ad1 = (const float*)d_in[4];
    const float* b1  = (const float*)d_in[5];
    const float* W2  = (const float*)d_in[6];
    const float* as2 = (const float*)d_in[7];
    const float* ad2 = (const float*)d_in[8];
    const float* b2  = (const float*)d_in[9];
    float* out = (float*)d_out;

    char* p = (char*)d_ws;
    auto alloc = [&](size_t bytes) {
        void* r = (void*)p;
        p += (bytes + 255) & ~size_t(255);
        return r;
    };
    int*            cnt   = (int*)alloc(NN * 4);
    int*            csr   = (int*)alloc((size_t)NN * CAP * 4);
    unsigned short* xl1   = (unsigned short*)alloc((size_t)NN * 64 * 2);
    float*          asrc1 = (float*)alloc((size_t)NN * 8 * 4);
    float*          adst1 = (float*)alloc((size_t)NN * 8 * 4);
    unsigned short* hbuf  = (unsigned short*)alloc((size_t)NN * 64 * 2);
    float*          asrc2 = (float*)alloc(NN * 4);
    float*          adst2 = (float*)alloc(NN * 4);
    float*          wsrc  = (float*)alloc(64 * 4);
    float*          wdst  = (float*)alloc(64 * 4);

    hipMemsetAsync(cnt, 0, NN * 4, stream);

    // layer-1 GEMM + padded-CSR scatter + watt GEMV (one dispatch, independent work)
    k_gemm1_scatter<<<GEMM1_BLOCKS + SCAT_BLOCKS + 1, 256, 0, stream>>>(
        x, W1, as1, ad1, ei, cnt, csr, W2, as2, ad2, wsrc, wdst, xl1, asrc1, adst1);

    k_gat1<<<NN / 4, 256, 0, stream>>>(cnt, csr, xl1, asrc1, adst1, b1,
                                       wsrc, wdst, hbuf, asrc2, adst2);
    k_gat2_out<<<NN / 4, 256, 0, stream>>>(cnt, csr, hbuf, asrc2, adst2,
                                           W2, b2, out);
}